// Round 18
// baseline (273.853 us; speedup 1.0000x reference)
//
#include <hip/hip_runtime.h>
#include <stdint.h>

#define MDIM 4096
#define KDIM 4096
#define NDIM 11008
#define KP   (KDIM/8)        // 512 packed int32 per N-row
#define NQB  (NDIM/32*32)    // -
#define QBLK ((NDIM/32)*32)  // 344*32 = 11008 repack blocks (n32 x kgroup)

typedef float  f32x4   __attribute__((ext_vector_type(4)));
typedef __bf16 bf16x8  __attribute__((ext_vector_type(8)));
typedef unsigned short u16x8 __attribute__((ext_vector_type(8)));
typedef int    i32x4   __attribute__((ext_vector_type(4)));
typedef int    i32x16  __attribute__((ext_vector_type(16)));
typedef char   c8x8    __attribute__((ext_vector_type(8)));
typedef char   c8x16   __attribute__((ext_vector_type(16)));

// RNE f32 -> bf16 bits (matches jax astype(bf16) for non-NaN inputs)
__device__ __forceinline__ unsigned short f2bf(float f) {
  uint32_t u = __builtin_bit_cast(uint32_t, f);
  u += 0x7FFFu + ((u >> 16) & 1u);
  return (unsigned short)(u >> 16);
}
__device__ __forceinline__ float bf2f(unsigned short h) {
  return __builtin_bit_cast(float, (uint32_t)h << 16);
}
__device__ __forceinline__ float bf16r(float f) { return bf2f(f2bf(f)); }

// ---------------- fused pre-pass (one dispatch) -----------------------------
// Fragment-major layouts: operand stored as 1KB blocks, one per (row32, k32):
//   blk[(r32)*128 + k32][lane*16 .. +16) = rows r32*32 + (lane&31),
//   k bytes k32*32 + (lane>>5)*16 .. +16   — exactly the i8 32x32x32 MFMA
//   fragment each lane needs (identical values to r10's LDS-fed reads).
// blocks [0, QBLK): W repack. block = (n32 = b>>5, kg = b&31); thread
//   (r=tid&31, half=(tid>>5)&1, j=tid>>6) reads 2 words (8B) of row
//   n32*32+r at word k32*4+half*2 (k32 = kg*4+j) — each 64B wq line is
//   consumed entirely by this block — and writes 16B dense into Q8f.
// blocks [QBLK, QBLK+MDIM): per-row x quant -> X8f frags + delta + exact
//   bf16 row-sum (z-term carries no quant error).
__global__ __launch_bounds__(256) void prepass_kernel(
    const uint32_t* __restrict__ wq, char* __restrict__ Q8f,
    const float* __restrict__ x, char* __restrict__ X8f,
    float* __restrict__ delta, float* __restrict__ xsum) {
  __shared__ float red[256];
  const int blk = blockIdx.x, t = threadIdx.x;
  if (blk < QBLK) {
    const int n32 = blk >> 5, kg = blk & 31;
    const int r = t & 31, half = (t >> 5) & 1, j = t >> 6;
    const int k32 = kg * 4 + j;
    const uint32_t* src = wq + (size_t)(n32 * 32 + r) * KP + k32 * 4 + half * 2;
    const uint32_t w0 = src[0], w1 = src[1];
    c8x16 v;
#pragma unroll
    for (int i = 0; i < 8; ++i) {
      v[i]     = (char)((w0 >> (4 * i)) & 0xF);
      v[8 + i] = (char)((w1 >> (4 * i)) & 0xF);
    }
    *(c8x16*)(Q8f + ((size_t)n32 * 128 + k32) * 1024 + (r + 32 * half) * 16) = v;
    return;
  }
  const int row = blk - QBLK;
  const float4* xr = (const float4*)(x + (size_t)row * KDIM);
  float xb[16];
#pragma unroll
  for (int i = 0; i < 4; ++i) {
    float4 f = xr[t * 4 + i];
    xb[i * 4 + 0] = bf16r(f.x); xb[i * 4 + 1] = bf16r(f.y);
    xb[i * 4 + 2] = bf16r(f.z); xb[i * 4 + 3] = bf16r(f.w);
  }
  float mx = 0.f, sm = 0.f;
#pragma unroll
  for (int j = 0; j < 16; ++j) { mx = fmaxf(mx, fabsf(xb[j])); sm += xb[j]; }
  red[t] = mx; __syncthreads();
  for (int o = 128; o > 0; o >>= 1) {
    if (t < o) red[t] = fmaxf(red[t], red[t + o]);
    __syncthreads();
  }
  const float rmx = red[0];
  __syncthreads();
  red[t] = sm; __syncthreads();
  for (int o = 128; o > 0; o >>= 1) {
    if (t < o) red[t] += red[t + o];
    __syncthreads();
  }
  const float rsm = red[0];
  const float inv = (rmx > 0.f) ? 127.0f / rmx : 0.f;
  if (t == 0) {
    delta[row] = (rmx > 0.f) ? rmx / 127.0f : 0.f;
    xsum[row]  = rsm;
  }
  c8x16 q;
#pragma unroll
  for (int j = 0; j < 16; ++j) q[j] = (char)__float2int_rn(xb[j] * inv);
  // thread t covers k = [t*16, t*16+16): k32 = t>>1, chunk = t&1
  const int lane16 = (row & 31) + 32 * (t & 1);
  *(c8x16*)(X8f + ((size_t)(row >> 5) * 128 + (t >> 1)) * 1024 + lane16 * 16) = q;
}

// ---------------- main GEMM: flatmm-style, NO LDS, NO barriers --------------
// 256x256 tile, 8 waves (2M x 4N), per-wave output 128x64 (acc[4][2]=128reg).
// Both operands are fragment-major in ws: each wave buffer_loads its 6 frags
// (A:4 + B:2, 1KB each, perfectly coalesced: uniform base + lane*16) per
// k32-step directly into VGPRs — the exact bytes r10's LDS path delivered,
// so MFMA inputs are bit-identical. Inner loop per k32:
//   VMWAIT(6) [this step's frags landed; next step's 6 in flight]
//   8x MFMA ; issue 6 loads for step+2 into the set just consumed.
// 2-deep named-register ring (static indexing, rule #20). Zero s_barrier,
// zero LDS: the r3-r17 wall (LDS-read pipe serializing with MFMA under
// barrier lockstep, 43% MfmaUtil plateau) is structurally removed; this is
// AITER flatmm's schedule (MFMA <-> buffer_load, counted vmcnt, never 0).
// VMEM: 48KB/CU per 585-cyc MFMA window; unique 16KB (4 waves share each
// A-frag, 2 share B) -> L1/L2-served, X8f+Q8f (61MB) L3-resident.
__global__ __launch_bounds__(512, 2) void gemm_i8f_kernel(
    const char* __restrict__ X8f, const char* __restrict__ Q8f,
    const float* __restrict__ delta, const float* __restrict__ xsum,
    const float* __restrict__ scales, const float* __restrict__ zeros,
    const float* __restrict__ bias, float* __restrict__ out) {
  const int tid  = threadIdx.x;
  const int lane = tid & 63;
  const int wave = tid >> 6;     // 0..7
  const int wm   = wave >> 2;    // 0..1 : M half (128 rows)
  const int wn   = wave & 3;     // 0..3 : N quarter (64 cols)

  // XCD-aware bijective swizzle: 688 = 8 * 86 blocks (r10 verbatim).
  const int b   = blockIdx.x;
  const int swz = (b & 7) * 86 + (b >> 3);
  const int mt  = swz / 43;
  const int nt  = swz - mt * 43;
  const int bm0 = mt * 256, bn0 = nt * 256;

  // fragment base pointers: frag(k32) lives at base + mf|nf*128KB + k32*1KB
  const char* aB = X8f + ((size_t)((bm0 >> 5) + wm * 4) * 128) * 1024
                       + (size_t)lane * 16;
  const char* bB = Q8f + ((size_t)((bn0 >> 5) + wn * 2) * 128) * 1024
                       + (size_t)lane * 16;

  i32x16 acc[4][2];
#pragma unroll
  for (int i = 0; i < 4; ++i)
#pragma unroll
    for (int j = 0; j < 2; ++j)
#pragma unroll
      for (int r = 0; r < 16; ++r) acc[i][j][r] = 0;

  i32x4 A0[4], B0[2], A1[4], B1[2];

#define LOADSET(AS, BS, K)                                                  \
  do {                                                                      \
    const size_t ko_ = (size_t)(K) * 1024;                                  \
    _Pragma("unroll") for (int mf = 0; mf < 4; ++mf)                        \
        AS[mf] = *(const i32x4*)(aB + (size_t)mf * 131072 + ko_);           \
    _Pragma("unroll") for (int nf = 0; nf < 2; ++nf)                        \
        BS[nf] = *(const i32x4*)(bB + (size_t)nf * 131072 + ko_);           \
  } while (0)

#define MFMA8(AS, BS)                                                       \
  __builtin_amdgcn_s_setprio(1);                                            \
  _Pragma("unroll") for (int mf = 0; mf < 4; ++mf)                          \
      _Pragma("unroll") for (int nf = 0; nf < 2; ++nf)                      \
          acc[mf][nf] = __builtin_amdgcn_mfma_i32_32x32x32_i8(              \
              AS[mf], BS[nf], acc[mf][nf], 0, 0, 0);                        \
  __builtin_amdgcn_s_setprio(0);

#define VMWAIT(N) asm volatile("s_waitcnt vmcnt(" #N ")" ::: "memory")

  // 128 k32 steps. Prologue: issue steps 0,1 (12 loads in flight).
  LOADSET(A0, B0, 0);
  LOADSET(A1, B1, 1);
  for (int k = 0; k < 126; k += 2) {
    VMWAIT(6);                 // step k landed; step k+1 in flight
    MFMA8(A0, B0);
    LOADSET(A0, B0, k + 2);    // refill consumed set (12 in flight)
    VMWAIT(6);                 // step k+1 landed; step k+2 in flight
    MFMA8(A1, B1);
    LOADSET(A1, B1, k + 3);
  }
  VMWAIT(6);
  MFMA8(A0, B0);               // step 126
  VMWAIT(0);
  MFMA8(A1, B1);               // step 127

#undef VMWAIT
#undef MFMA8
#undef LOADSET

  // epilogue (verbatim r10): C/D 32x32 layout col=lane&31,
  // row=(reg&3)+8*(reg>>2)+4*(lane>>5).
  // out = acc * (Delta_m * bf16(s_n)) + bf16(z_n) * xsum_m + bias_n
  const int colv = bn0 + wn * 64 + (lane & 31);
  const int rowb = bm0 + wm * 128 + ((lane >> 5) << 2);
  float sb[2], zb[2], bv[2];
#pragma unroll
  for (int nf = 0; nf < 2; ++nf) {
    sb[nf] = bf16r(scales[colv + nf * 32]);
    zb[nf] = bf16r(zeros[colv + nf * 32]);
    bv[nf] = bias[colv + nf * 32];
  }
#pragma unroll
  for (int mf = 0; mf < 4; ++mf)
#pragma unroll
    for (int reg = 0; reg < 16; ++reg) {
      const int row = rowb + mf * 32 + (reg & 3) + ((reg >> 2) << 3);
      const float dm = delta[row];
      const float xm = xsum[row];
#pragma unroll
      for (int nf = 0; nf < 2; ++nf)
        out[(size_t)row * NDIM + colv + nf * 32] =
            (float)acc[mf][nf][reg] * (dm * sb[nf]) + (zb[nf] * xm + bv[nf]);
    }
}

// ---------------- fallback fused 128x128 bf16 kernel (ws too small) ---------
__global__ __launch_bounds__(256, 3) void gemm_fused_kernel(
    const float* __restrict__ x, const uint32_t* __restrict__ wq,
    const float* __restrict__ scales, const float* __restrict__ zeros,
    const float* __restrict__ bias, float* __restrict__ out) {
  __shared__ __align__(16) char smem[2 * 128 * 64 * 2];
  char* As = smem;
  char* Bs = smem + 16384;

  const int tid  = threadIdx.x;
  const int lane = tid & 63;
  const int wave = tid >> 6;
  const int wm = wave >> 1, wn = wave & 1;

  const int b   = blockIdx.x;
  const int swz = (b & 7) * 344 + (b >> 3);
  const int mt  = swz / 86;
  const int nt  = swz - mt * 86;
  const int bm0 = mt * 128, bn0 = nt * 128;

  f32x4 acc[4][4];
#pragma unroll
  for (int i = 0; i < 4; ++i)
#pragma unroll
    for (int j = 0; j < 4; ++j) acc[i][j] = (f32x4){0.f, 0.f, 0.f, 0.f};

  const int base_a = ((wm * 64 + (lane & 15)) << 7) + ((lane >> 4) << 4);
  const int base_b = ((wn * 64 + (lane & 15)) << 7) + ((lane >> 4) << 4);

  float sv[4], zv[4];
#pragma unroll
  for (int it = 0; it < 4; ++it) {
    int r = bn0 + it * 32 + (tid >> 3);
    sv[it] = bf16r(scales[r]);
    zv[it] = bf16r(zeros[r]);
  }

  for (int kt = 0; kt < KDIM / 64; ++kt) {
    const int k0 = kt * 64;
    __syncthreads();
#pragma unroll
    for (int it = 0; it < 4; ++it) {
      int ch = it * 256 + tid;
      int row = ch >> 3, c8 = ch & 7;
      const float* src = x + (size_t)(bm0 + row) * KDIM + k0 + c8 * 8;
      float4 f0 = *(const float4*)src;
      float4 f1 = *(const float4*)(src + 4);
      u16x8 v;
      v[0] = f2bf(f0.x); v[1] = f2bf(f0.y); v[2] = f2bf(f0.z); v[3] = f2bf(f0.w);
      v[4] = f2bf(f1.x); v[5] = f2bf(f1.y); v[6] = f2bf(f1.z); v[7] = f2bf(f1.w);
      *(u16x8*)(As + row * 128 + c8 * 16) = v;
    }
#pragma unroll
    for (int it = 0; it < 4; ++it) {
      int ch = it * 256 + tid;
      int row = ch >> 3, kp = ch & 7;
      uint32_t w = wq[(size_t)(bn0 + row) * KP + kt * 8 + kp];
      float s = sv[it], z = zv[it];
      u16x8 v;
#pragma unroll
      for (int j = 0; j < 8; ++j) {
        float qf = (float)((w >> (4 * j)) & 0xF);
        float t  = bf16r(qf * s);
        v[j] = f2bf(t + z);
      }
      *(u16x8*)(Bs + row * 128 + kp * 16) = v;
    }
    __syncthreads();
#pragma unroll
    for (int ks = 0; ks < 2; ++ks) {
      bf16x8 af[4], bf[4];
#pragma unroll
      for (int i = 0; i < 4; ++i)
        af[i] = *(const bf16x8*)(As + base_a + i * 2048 + ks * 64);
#pragma unroll
      for (int j = 0; j < 4; ++j)
        bf[j] = *(const bf16x8*)(Bs + base_b + j * 2048 + ks * 64);
#pragma unroll
      for (int i = 0; i < 4; ++i)
#pragma unroll
        for (int j = 0; j < 4; ++j)
          acc[i][j] = __builtin_amdgcn_mfma_f32_16x16x32_bf16(af[i], bf[j],
                                                              acc[i][j], 0, 0, 0);
    }
  }

  const int colbase = bn0 + wn * 64 + (lane & 15);
  const int rowbase = bm0 + wm * 64 + ((lane >> 4) << 2);
  float bv[4];
#pragma unroll
  for (int j = 0; j < 4; ++j) bv[j] = bias[colbase + j * 16];
#pragma unroll
  for (int i = 0; i < 4; ++i) {
#pragma unroll
    for (int j = 0; j < 4; ++j) {
      size_t base = (size_t)(rowbase + i * 16) * NDIM + colbase + j * 16;
#pragma unroll
      for (int r = 0; r < 4; ++r)
        out[base + (size_t)r * NDIM] = acc[i][j][r] + bv[j];
    }
  }
}

extern "C" void kernel_launch(void* const* d_in, const int* in_sizes, int n_in,
                              void* d_out, int out_size, void* d_ws, size_t ws_size,
                              hipStream_t stream) {
  const float*    x      = (const float*)d_in[0];
  const uint32_t* wq     = (const uint32_t*)d_in[1];
  const float*    scales = (const float*)d_in[2];
  const float*    zeros  = (const float*)d_in[3];
  const float*    bias   = (const float*)d_in[4];
  float*          out    = (float*)d_out;

  const size_t offQ = 0;
  const size_t szQ  = (size_t)NDIM * KDIM;           // 45,088,768
  const size_t offX = szQ;
  const size_t szX  = (size_t)MDIM * KDIM;           // 16,777,216
  const size_t offD = offX + szX;                    // 61,865,984
  const size_t offS = offD + MDIM * sizeof(float);
  const size_t need = offS + MDIM * sizeof(float);   // ~61.9 MB

  if (ws_size >= need) {
    char*  Q8f   = (char*)d_ws + offQ;
    char*  X8f   = (char*)d_ws + offX;
    float* dlt   = (float*)((char*)d_ws + offD);
    float* xsm   = (float*)((char*)d_ws + offS);
    prepass_kernel<<<QBLK + MDIM, 256, 0, stream>>>(wq, Q8f, x, X8f, dlt, xsm);
    gemm_i8f_kernel<<<688, 512, 0, stream>>>(X8f, Q8f, dlt, xsm, scales, zeros,
                                             bias, out);
  } else {
    gemm_fused_kernel<<<2752, 256, 0, stream>>>(x, wq, scales, zeros, bias, out);
  }
}

// Round 19
// 226.740 us; speedup vs baseline: 1.2078x; 1.2078x over previous
//
#include <hip/hip_runtime.h>
#include <stdint.h>

#define MDIM 4096
#define KDIM 4096
#define NDIM 11008
#define KP   (KDIM/8)          // 512 packed int32 per N-row
#define NQB  (NDIM*KP/512)     // 11008 repack blocks (2 words/thread)

typedef float  f32x4   __attribute__((ext_vector_type(4)));
typedef __bf16 bf16x8  __attribute__((ext_vector_type(8)));
typedef unsigned short u16x8 __attribute__((ext_vector_type(8)));
typedef int    i32x4   __attribute__((ext_vector_type(4)));
typedef int    i32x16  __attribute__((ext_vector_type(16)));
typedef char   c8x16   __attribute__((ext_vector_type(16)));

// RNE f32 -> bf16 bits (matches jax astype(bf16) for non-NaN inputs)
__device__ __forceinline__ unsigned short f2bf(float f) {
  uint32_t u = __builtin_bit_cast(uint32_t, f);
  u += 0x7FFFu + ((u >> 16) & 1u);
  return (unsigned short)(u >> 16);
}
__device__ __forceinline__ float bf2f(unsigned short h) {
  return __builtin_bit_cast(float, (uint32_t)h << 16);
}
__device__ __forceinline__ float bf16r(float f) { return bf2f(f2bf(f)); }

// async global -> LDS, 16B per lane, wave-uniform LDS base + lane*16
__device__ __forceinline__ void lds16(const void* g, void* l) {
  __builtin_amdgcn_global_load_lds(
      (const __attribute__((address_space(1))) unsigned int*)g,
      (__attribute__((address_space(3))) unsigned int*)l, 16, 0, 0);
}

// ---------------- fused pre-pass: repack W + quantize X in ONE dispatch -----
// blocks [0, NQB): unpack int4 -> int8 Q8[N][K], 2 words/thread, one 16B
// store (vs r17's 8B). blocks [NQB, NQB+MDIM): per-row x quant -> X8 +
// delta + exact bf16 row-sum (z-term carries no quant error).
__global__ __launch_bounds__(256) void prepass_kernel(
    const uint32_t* __restrict__ wq, c8x16* __restrict__ Q8,
    const float* __restrict__ x, c8x16* __restrict__ X8,
    float* __restrict__ delta, float* __restrict__ xsum) {
  __shared__ float red[256];
  const int blk = blockIdx.x, t = threadIdx.x;
  if (blk < NQB) {
    int idx = blk * 256 + t;                  // [0, N*KP/2)
    uint32_t w0 = wq[2 * idx], w1 = wq[2 * idx + 1];
    c8x16 v;
#pragma unroll
    for (int j = 0; j < 8; ++j) {
      v[j]     = (char)((w0 >> (4 * j)) & 0xF);
      v[8 + j] = (char)((w1 >> (4 * j)) & 0xF);
    }
    Q8[idx] = v;
    return;
  }
  const int row = blk - NQB;
  const float4* xr = (const float4*)(x + (size_t)row * KDIM);
  float xb[16];
#pragma unroll
  for (int i = 0; i < 4; ++i) {
    float4 f = xr[t * 4 + i];
    xb[i * 4 + 0] = bf16r(f.x); xb[i * 4 + 1] = bf16r(f.y);
    xb[i * 4 + 2] = bf16r(f.z); xb[i * 4 + 3] = bf16r(f.w);
  }
  float mx = 0.f, sm = 0.f;
#pragma unroll
  for (int j = 0; j < 16; ++j) { mx = fmaxf(mx, fabsf(xb[j])); sm += xb[j]; }
  red[t] = mx; __syncthreads();
  for (int o = 128; o > 0; o >>= 1) {
    if (t < o) red[t] = fmaxf(red[t], red[t + o]);
    __syncthreads();
  }
  const float rmx = red[0];
  __syncthreads();
  red[t] = sm; __syncthreads();
  for (int o = 128; o > 0; o >>= 1) {
    if (t < o) red[t] += red[t + o];
    __syncthreads();
  }
  const float rsm = red[0];
  const float inv = (rmx > 0.f) ? 127.0f / rmx : 0.f;
  if (t == 0) {
    delta[row] = (rmx > 0.f) ? rmx / 127.0f : 0.f;
    xsum[row]  = rsm;
  }
  c8x16 q;
#pragma unroll
  for (int j = 0; j < 16; ++j) q[j] = (char)__float2int_rn(xb[j] * inv);
  X8[(size_t)row * 256 + t] = q;
}

// ---------------- main GEMM: 256x256, BK=128, 8 waves, i8 32x32x32 ----------
// VERBATIM round-10/17 winner (GEMM 194us, MfmaUtil 43%, 0 bank conflicts):
// 4-slot K-half ring (A 4x16KB at 0, B at +64KB), 4-phase TILE with counted
// VMWAIT(8) (waits one phase before the dependent read, one-barrier WAR
// separation on slot recycle), chunk-permutation selector b3 (the proven
// zero-conflict read pattern), XCD-bijective block swizzle.
// Structure-space record (r11-r18): 2-blk/CU, barrier-free, 4-wave, 256x128,
// and LDS-free flatmm variants all measured 200-250us or failed; this config
// is the measured optimum of the family (plain-HIP lockstep plateau, m233).
__global__ __launch_bounds__(512, 2) void gemm256_i8_kernel(
    const char* __restrict__ A8, const char* __restrict__ Q8,
    const float* __restrict__ delta, const float* __restrict__ xsum,
    const float* __restrict__ scales, const float* __restrict__ zeros,
    const float* __restrict__ bias, float* __restrict__ out) {
  __shared__ __align__(16) char smem[131072];

  const int tid  = threadIdx.x;
  const int lane = tid & 63;
  const int wave = tid >> 6;     // 0..7
  const int wm   = wave >> 2;    // 0..1 : M half (128 rows)
  const int wn   = wave & 3;     // 0..3 : N quarter (64 cols)

  // XCD-aware bijective swizzle: 688 = 8 * 86 blocks.
  const int b   = blockIdx.x;
  const int swz = (b & 7) * 86 + (b >> 3);
  const int mt  = swz / 43;
  const int nt  = swz - mt * 43;
  const int bm0 = mt * 256, bn0 = nt * 256;

  // staging geometry: lane l writes subtile bytes [l*16, l*16+16):
  // row srow = l>>2, stored position schunk = l&3; source global chunk =
  // schunk ^ (b3(srow)<<1) (^1 for the odd subtile).
  const int srow   = lane >> 2;
  const int schunk = lane & 3;
  const int perm0  = schunk ^ (((srow >> 3) & 1) << 1);
  const int perm1  = perm0 ^ 1;
  const char* aR  = A8 + (size_t)(bm0 + wave * 32 + srow) * KDIM + perm0 * 16;
  const char* aR2 = A8 + (size_t)(bm0 + wave * 32 + 16 + srow) * KDIM + perm1 * 16;
  const char* bR  = Q8 + (size_t)(bn0 + wave * 32 + srow) * KDIM + perm0 * 16;
  const char* bR2 = Q8 + (size_t)(bn0 + wave * 32 + 16 + srow) * KDIM + perm1 * 16;

  // fragment read offset for ks32 step s=0 (rd0) / s=1 (rd1 = rd0^32).
  // bank-quad bits: {bit6 = r15&1, bit5 = b3^s, bit4 = hk^sub} — the
  // proven zero-conflict pattern.
  const int r31 = lane & 31;
  const int sub = r31 >> 4;
  const int r15 = r31 & 15;
  const int hk  = lane >> 5;
  const int rd0 = sub * 1024 + r15 * 64 + ((hk ^ sub) << 4) + ((r15 & 8) << 2);
  const int rd1 = rd0 ^ 32;

  const int aoffc = wm * 8192;          // wm*8 subtiles (128 rows)
  const int boffc = 65536 + wn * 4096;  // B ring + wn*4 subtiles (64 rows)

  i32x16 acc[4][2];
#pragma unroll
  for (int i = 0; i < 4; ++i)
#pragma unroll
    for (int j = 0; j < 2; ++j)
#pragma unroll
      for (int r = 0; r < 16; ++r) acc[i][j][r] = 0;

  i32x4 Af[4], Bf[2];

#define STAGE_A(tile, h, slot)                                              \
  do {                                                                      \
    const size_t ko_ = (size_t)((tile) * 128 + (h) * 64);                   \
    char* d_ = smem + ((slot) << 14) + wave * 2048;                         \
    lds16(aR + ko_, d_);                                                    \
    lds16(aR2 + ko_, d_ + 1024);                                            \
  } while (0)

#define STAGE_B(tile, h, slot)                                              \
  do {                                                                      \
    const size_t ko_ = (size_t)((tile) * 128 + (h) * 64);                   \
    char* d_ = smem + 65536 + ((slot) << 14) + wave * 2048;                 \
    lds16(bR + ko_, d_);                                                    \
    lds16(bR2 + ko_, d_ + 1024);                                            \
  } while (0)

#define READ6(slotbase, S)                                                  \
  do {                                                                      \
    const int ro_ = (S) ? rd1 : rd0;                                        \
    _Pragma("unroll") for (int mf = 0; mf < 4; ++mf)                        \
        Af[mf] = *(const i32x4*)(smem + aoffc + (slotbase) +                \
                                 mf * 2048 + ro_);                          \
    _Pragma("unroll") for (int nf = 0; nf < 2; ++nf)                        \
        Bf[nf] = *(const i32x4*)(smem + boffc + (slotbase) +                \
                                 nf * 2048 + ro_);                          \
  } while (0)

#define MFMA8()                                                             \
  __builtin_amdgcn_s_setprio(1);                                            \
  _Pragma("unroll") for (int mf = 0; mf < 4; ++mf)                          \
      _Pragma("unroll") for (int nf = 0; nf < 2; ++nf)                      \
          acc[mf][nf] = __builtin_amdgcn_mfma_i32_32x32x32_i8(              \
              Af[mf], Bf[nf], acc[mf][nf], 0, 0, 0);                        \
  __builtin_amdgcn_s_setprio(0);

#define BAR                                                                 \
  __builtin_amdgcn_s_barrier();                                             \
  __builtin_amdgcn_sched_barrier(0);

#define VMWAIT(N) asm volatile("s_waitcnt vmcnt(" #N ")" ::: "memory")

  // 4 phases/K-tile: (h0,s0),(h0,s1),(h1,s0),(h1,s1). Staging: p0 A(T+1,h1),
  // p1 B(T+1,h1) + VM, p2 A(T+2,h0)->S0s (recycle), p3 B(T+2,h0) + VM.
#define TILE(T, S0s, S1s, SN1s, NSTG, VM1STMT, VM3STMT)                     \
  do {                                                                      \
    READ6((S0s) << 14, 0);                                                  \
    if ((NSTG) >= 1) STAGE_A((T) + 1, 1, SN1s);                             \
    BAR; MFMA8(); BAR;                                                      \
    READ6((S0s) << 14, 1);                                                  \
    if ((NSTG) >= 2) STAGE_B((T) + 1, 1, SN1s);                             \
    VM1STMT;                                                                \
    BAR; MFMA8(); BAR;                                                      \
    READ6((S1s) << 14, 0);                                                  \
    if ((NSTG) >= 3) STAGE_A((T) + 2, 0, S0s);                              \
    BAR; MFMA8(); BAR;                                                      \
    READ6((S1s) << 14, 1);                                                  \
    if ((NSTG) >= 4) STAGE_B((T) + 2, 0, S0s);                              \
    VM3STMT;                                                                \
    BAR; MFMA8(); BAR;                                                      \
  } while (0)

  // prologue: (0,h0)->s0, (0,h1)->s1, (1,h0)->s2 = 12 loads; retire first 4
  STAGE_A(0, 0, 0);
  STAGE_B(0, 0, 0);
  STAGE_A(0, 1, 1);
  STAGE_B(0, 1, 1);
  STAGE_A(1, 0, 2);
  STAGE_B(1, 0, 2);
  VMWAIT(8);
  BAR;

  for (int tt = 0; tt < 30; tt += 2) {
    TILE(tt,     0, 1, 3, 4, VMWAIT(8), VMWAIT(8));
    TILE(tt + 1, 2, 3, 1, 4, VMWAIT(8), VMWAIT(8));
  }
  // T=30: stage only (31,h1); T=31: no staging, drain
  TILE(30, 0, 1, 3, 2, VMWAIT(8), VMWAIT(4));
  TILE(31, 2, 3, 1, 0, VMWAIT(0), (void)0);

#undef TILE
#undef VMWAIT
#undef BAR
#undef MFMA8
#undef READ6
#undef STAGE_B
#undef STAGE_A

  // epilogue: C/D 32x32 layout col=lane&31, row=(reg&3)+8*(reg>>2)+4*(lane>>5)
  // out = acc * (Delta_m * bf16(s_n)) + bf16(z_n) * xsum_m + bias_n
  const int colv = bn0 + wn * 64 + (lane & 31);
  const int rowb = bm0 + wm * 128 + ((lane >> 5) << 2);
  float sb[2], zb[2], bv[2];
#pragma unroll
  for (int nf = 0; nf < 2; ++nf) {
    sb[nf] = bf16r(scales[colv + nf * 32]);
    zb[nf] = bf16r(zeros[colv + nf * 32]);
    bv[nf] = bias[colv + nf * 32];
  }
#pragma unroll
  for (int mf = 0; mf < 4; ++mf)
#pragma unroll
    for (int reg = 0; reg < 16; ++reg) {
      const int row = rowb + mf * 32 + (reg & 3) + ((reg >> 2) << 3);
      const float dm = delta[row];
      const float xm = xsum[row];
#pragma unroll
      for (int nf = 0; nf < 2; ++nf)
        out[(size_t)row * NDIM + colv + nf * 32] =
            (float)acc[mf][nf][reg] * (dm * sb[nf]) + (zb[nf] * xm + bv[nf]);
    }
}

// ---------------- fallback fused 128x128 bf16 kernel (ws too small) ---------
__global__ __launch_bounds__(256, 3) void gemm_fused_kernel(
    const float* __restrict__ x, const uint32_t* __restrict__ wq,
    const float* __restrict__ scales, const float* __restrict__ zeros,
    const float* __restrict__ bias, float* __restrict__ out) {
  __shared__ __align__(16) char smem[2 * 128 * 64 * 2];
  char* As = smem;
  char* Bs = smem + 16384;

  const int tid  = threadIdx.x;
  const int lane = tid & 63;
  const int wave = tid >> 6;
  const int wm = wave >> 1, wn = wave & 1;

  const int b   = blockIdx.x;
  const int swz = (b & 7) * 344 + (b >> 3);
  const int mt  = swz / 86;
  const int nt  = swz - mt * 86;
  const int bm0 = mt * 128, bn0 = nt * 128;

  f32x4 acc[4][4];
#pragma unroll
  for (int i = 0; i < 4; ++i)
#pragma unroll
    for (int j = 0; j < 4; ++j) acc[i][j] = (f32x4){0.f, 0.f, 0.f, 0.f};

  const int base_a = ((wm * 64 + (lane & 15)) << 7) + ((lane >> 4) << 4);
  const int base_b = ((wn * 64 + (lane & 15)) << 7) + ((lane >> 4) << 4);

  float sv[4], zv[4];
#pragma unroll
  for (int it = 0; it < 4; ++it) {
    int r = bn0 + it * 32 + (tid >> 3);
    sv[it] = bf16r(scales[r]);
    zv[it] = bf16r(zeros[r]);
  }

  for (int kt = 0; kt < KDIM / 64; ++kt) {
    const int k0 = kt * 64;
    __syncthreads();
#pragma unroll
    for (int it = 0; it < 4; ++it) {
      int ch = it * 256 + tid;
      int row = ch >> 3, c8 = ch & 7;
      const float* src = x + (size_t)(bm0 + row) * KDIM + k0 + c8 * 8;
      float4 f0 = *(const float4*)src;
      float4 f1 = *(const float4*)(src + 4);
      u16x8 v;
      v[0] = f2bf(f0.x); v[1] = f2bf(f0.y); v[2] = f2bf(f0.z); v[3] = f2bf(f0.w);
      v[4] = f2bf(f1.x); v[5] = f2bf(f1.y); v[6] = f2bf(f1.z); v[7] = f2bf(f1.w);
      *(u16x8*)(As + row * 128 + c8 * 16) = v;
    }
#pragma unroll
    for (int it = 0; it < 4; ++it) {
      int ch = it * 256 + tid;
      int row = ch >> 3, kp = ch & 7;
      uint32_t w = wq[(size_t)(bn0 + row) * KP + kt * 8 + kp];
      float s = sv[it], z = zv[it];
      u16x8 v;
#pragma unroll
      for (int j = 0; j < 8; ++j) {
        float qf = (float)((w >> (4 * j)) & 0xF);
        float t  = bf16r(qf * s);
        v[j] = f2bf(t + z);
      }
      *(u16x8*)(Bs + row * 128 + kp * 16) = v;
    }
    __syncthreads();
#pragma unroll
    for (int ks = 0; ks < 2; ++ks) {
      bf16x8 af[4], bf[4];
#pragma unroll
      for (int i = 0; i < 4; ++i)
        af[i] = *(const bf16x8*)(As + base_a + i * 2048 + ks * 64);
#pragma unroll
      for (int j = 0; j < 4; ++j)
        bf[j] = *(const bf16x8*)(Bs + base_b + j * 2048 + ks * 64);
#pragma unroll
      for (int i = 0; i < 4; ++i)
#pragma unroll
        for (int j = 0; j < 4; ++j)
          acc[i][j] = __builtin_amdgcn_mfma_f32_16x16x32_bf16(af[i], bf[j],
                                                              acc[i][j], 0, 0, 0);
    }
  }

  const int colbase = bn0 + wn * 64 + (lane & 15);
  const int rowbase = bm0 + wm * 64 + ((lane >> 4) << 2);
  float bv[4];
#pragma unroll
  for (int j = 0; j < 4; ++j) bv[j] = bias[colbase + j * 16];
#pragma unroll
  for (int i = 0; i < 4; ++i) {
#pragma unroll
    for (int j = 0; j < 4; ++j) {
      size_t base = (size_t)(rowbase + i * 16) * NDIM + colbase + j * 16;
#pragma unroll
      for (int r = 0; r < 4; ++r)
        out[base + (size_t)r * NDIM] = acc[i][j][r] + bv[j];
    }
  }
}

extern "C" void kernel_launch(void* const* d_in, const int* in_sizes, int n_in,
                              void* d_out, int out_size, void* d_ws, size_t ws_size,
                              hipStream_t stream) {
  const float*    x      = (const float*)d_in[0];
  const uint32_t* wq     = (const uint32_t*)d_in[1];
  const float*    scales = (const float*)d_in[2];
  const float*    zeros  = (const float*)d_in[3];
  const float*    bias   = (const float*)d_in[4];
  float*          out    = (float*)d_out;

  const size_t offQ = 0;
  const size_t szQ  = (size_t)NDIM * KDIM;           // 45,088,768
  const size_t offX = szQ;
  const size_t szX  = (size_t)MDIM * KDIM;           // 16,777,216
  const size_t offD = offX + szX;                    // 61,865,984
  const size_t offS = offD + MDIM * sizeof(float);
  const size_t need = offS + MDIM * sizeof(float);   // ~61.9 MB

  if (ws_size >= need) {
    char*  Q8    = (char*)d_ws + offQ;
    char*  X8    = (char*)d_ws + offX;
    float* dlt   = (float*)((char*)d_ws + offD);
    float* xsm   = (float*)((char*)d_ws + offS);
    prepass_kernel<<<NQB + MDIM, 256, 0, stream>>>(wq, (c8x16*)Q8, x,
                                                   (c8x16*)X8, dlt, xsm);
    gemm256_i8_kernel<<<688, 512, 0, stream>>>(X8, Q8, dlt, xsm, scales, zeros,
                                               bias, out);
  } else {
    gemm_fused_kernel<<<2752, 256, 0, stream>>>(x, wq, scales, zeros, bias, out);
  }
}